// Round 3
// baseline (303.208 us; speedup 1.0000x reference)
//
#include <hip/hip_runtime.h>
#include <hip/hip_bf16.h>
#include <math.h>

// Problem constants
#define NCLS   19
#define KPC    100
#define NA     1900       // anchors (also first NA contrast cols)
#define NM     20000      // memory rows
#define NC     21900      // contrast rows = NA + NM
#define NCP2   22016      // contrast cols padded to multiple of 128
#define D      256        // feature dim
#define HW     16384      // 128*128
#define NPIX   131072     // 8*128*128
#define NT_M   15         // 1920/128 m-tiles
#define NGRP   34         // n-tile groups (172 tiles: groups 0,1 take 6, rest 5)

typedef __attribute__((ext_vector_type(8))) short bf16x8;
typedef __attribute__((ext_vector_type(4))) float f32x4;

// workspace byte offsets
#define WS_IDX   0         // 1900 ints
#define WS_ROWS  7680      // 1920 f
#define WS_ROWP  15360     // 1920 f
#define WS_HIST  23040     // 19 ints
#define WS_TKT   23168     // 1 int
#define WS_CLAB  23296     // 22016 ints
#define WS_CT2   111616    // bf16 [32 kq][22016 n][8] = 11,272,192 B

__device__ __forceinline__ short f2bf(float x) {
    __hip_bfloat16 h = __float2bfloat16(x);
    return *(short*)&h;
}

// ---------------- K0: memory normalize + labels + zeros + histogram ----------------
__global__ void prep_kernel(const float* __restrict__ mem, const int* __restrict__ memlab,
                            float* rowS, float* rowP, int* clab, int* hist, int* ticket,
                            short* __restrict__ Ct2) {
    const int b = blockIdx.x, t = threadIdx.x;
    if (b < 2500) {                       // normalize memory rows -> Ct2 cols NA..NC
        const int r = b * 8 + (t >> 5);
        const int kq = t & 31;
        const float4 v0 = *(const float4*)(mem + (size_t)r * D + kq * 8);
        const float4 v1 = *(const float4*)(mem + (size_t)r * D + kq * 8 + 4);
        float ssq = v0.x*v0.x + v0.y*v0.y + v0.z*v0.z + v0.w*v0.w
                  + v1.x*v1.x + v1.y*v1.y + v1.z*v1.z + v1.w*v1.w;
        #pragma unroll
        for (int o = 16; o; o >>= 1) ssq += __shfl_xor(ssq, o, 32);
        const float inv = 1.0f / fmaxf(sqrtf(ssq), 1e-12f);
        bf16x8 outv;
        outv[0] = f2bf(v0.x * inv); outv[1] = f2bf(v0.y * inv);
        outv[2] = f2bf(v0.z * inv); outv[3] = f2bf(v0.w * inv);
        outv[4] = f2bf(v1.x * inv); outv[5] = f2bf(v1.y * inv);
        outv[6] = f2bf(v1.z * inv); outv[7] = f2bf(v1.w * inv);
        *(bf16x8*)(Ct2 + ((size_t)kq * NCP2 + NA + r) * 8) = outv;
    } else if (b < 2586) {                // labels + zero accumulators + zero pad cols
        const int i = (b - 2500) * 256 + t;     // 0..22015
        clab[i] = (i < NA) ? ((i * 5243) >> 19)
                           : ((i < NC) ? memlab[i - NA] : -1);
        if (i < 1920) { rowS[i] = 0.f; rowP[i] = 0.f; }
        if (i < 32 * (NCP2 - NC)) {
            const int kq = i / (NCP2 - NC);
            const int n  = NC + (i - kq * (NCP2 - NC));
            bf16x8 z = {};
            *(bf16x8*)(Ct2 + ((size_t)kq * NCP2 + n) * 8) = z;
        }
    } else {                              // b==2586: class histogram + ticket
        __shared__ int h[NCLS];
        if (t < NCLS) h[t] = 0;
        if (t == 32) *ticket = 0;
        __syncthreads();
        for (int i = t; i < NM; i += 256) atomicAdd(&h[memlab[i]], 1);
        __syncthreads();
        if (t < NCLS) hist[t] = h[t];
    }
}

// ---------------- K1: first-K-per-class sampler (ascending order) ----------------
__global__ void sample_kernel(const int* __restrict__ labels, int* __restrict__ idx) {
    const int c = blockIdx.x;
    const int t = threadIdx.x;
    const int wave = t >> 6, lane = t & 63;
    __shared__ int s_base;
    __shared__ int s_wavecnt[4];
    if (t == 0) s_base = 0;
    __syncthreads();
    for (int start = 0; start < NPIX; start += 256) {
        const int i = start + t;
        const bool pred = (labels[i] == c);
        const unsigned long long b = __ballot(pred);
        if (lane == 0) s_wavecnt[wave] = __popcll(b);
        __syncthreads();
        const int base = s_base;
        int wbase = 0;
        for (int w = 0; w < wave; ++w) wbase += s_wavecnt[w];
        const int chunk_total = s_wavecnt[0] + s_wavecnt[1] + s_wavecnt[2] + s_wavecnt[3];
        if (pred) {
            const int rank = base + wbase + __popcll(b & ((1ULL << lane) - 1ULL));
            if (rank < KPC) idx[c * KPC + rank] = i;
        }
        __syncthreads();
        if (t == 0) s_base = base + chunk_total;
        if (base + chunk_total >= KPC) break;
    }
}

// ---------------- K2: gather + normalize anchors -> Ct2 cols 0..1899 ----------------
__global__ void anchor_kernel(const float* __restrict__ pixel, const int* __restrict__ idx,
                              short* __restrict__ Ct2) {
    const int t = threadIdx.x;
    const int a = blockIdx.x * 8 + (t >> 5);
    const int kq = t & 31;
    if (a >= NA) return;
    const int p = idx[a];
    const int b = p >> 14;
    const int hw = p & (HW - 1);
    const float* base = pixel + ((size_t)(b * D + kq * 8)) * HW + hw;
    float v[8];
    float ssq = 0.f;
    #pragma unroll
    for (int j = 0; j < 8; ++j) { v[j] = base[(size_t)j * HW]; ssq += v[j] * v[j]; }
    #pragma unroll
    for (int o = 16; o; o >>= 1) ssq += __shfl_xor(ssq, o, 32);
    const float inv = 1.0f / fmaxf(sqrtf(ssq), 1e-12f);
    bf16x8 outv;
    #pragma unroll
    for (int j = 0; j < 8; ++j) outv[j] = f2bf(v[j] * inv);
    *(bf16x8*)(Ct2 + ((size_t)kq * NCP2 + a) * 8) = outv;
}

// ---------------- K3: persistent-A MFMA GEMM + fused epilogue + finalize ----------------
// Block: 128-row m-strip (A resident in 64KB LDS, staged once) x ~5 n-tiles.
// B streams through double-buffered 2x8KB chunks (32 dims each). 80KB LDS = 2 blocks/CU.
__global__ __launch_bounds__(256, 2)
void gemm_kernel(const short* __restrict__ Ct2, const int* __restrict__ clab,
                 float* __restrict__ rowS, float* __restrict__ rowP,
                 const int* __restrict__ hist, int* ticket, float* __restrict__ out) {
    __shared__ __align__(16) short lds[40960];      // 80 KB exactly
    short* As = lds;                                 // [32 kq][128 m][8]
    short* Bs = lds + 32768;                         // [2 buf][4 kq][128 n][8]
    const int tid  = threadIdx.x;
    const int lane = tid & 63;
    const int w    = tid >> 6;
    const int wm   = w >> 1, wn = w & 1;
    const int quad = lane >> 4;
    const int l16  = lane & 15;
    const int mt   = blockIdx.x;        // 0..14
    const int g    = blockIdx.y;        // 0..33
    const int m0   = mt * 128;
    const int NTILE = (g < 2) ? 6 : 5;
    const int NCH   = NTILE * 8;

    // stage full-K A-strip once
    #pragma unroll
    for (int i = 0; i < 16; ++i) {
        const int c  = w * 16 + i;
        const int kq = c >> 1;
        const int ml = (c & 1) * 64;
        const size_t gA = ((size_t)kq * NCP2 + m0 + ml + lane) * 8;
        __builtin_amdgcn_global_load_lds(
            (const __attribute__((address_space(1))) void*)(Ct2 + gA),
            (__attribute__((address_space(3))) void*)(As + ((size_t)(kq * 128 + ml)) * 8 + lane * 8),
            16, 0, 0);
    }

    auto issueB = [&](int c, int buf) {
        const int n0  = (g + NGRP * (c >> 3)) * 128;
        const int kq0 = (c & 7) * 4;
        #pragma unroll
        for (int i = 0; i < 2; ++i) {
            const int cc  = w * 2 + i;
            const int kql = cc >> 1;
            const int nl  = (cc & 1) * 64;
            const size_t gB = ((size_t)(kq0 + kql) * NCP2 + n0 + nl + lane) * 8;
            __builtin_amdgcn_global_load_lds(
                (const __attribute__((address_space(1))) void*)(Ct2 + gB),
                (__attribute__((address_space(3))) void*)(Bs + (size_t)buf * 4096 + (kql * 128 + nl) * 8 + lane * 8),
                16, 0, 0);
        }
    };

    issueB(0, 0);
    f32x4 acc[4][4] = {};

    for (int c = 0; c < NCH; ++c) {
        __syncthreads();                        // drains loads issued one compute-phase ago
        if (c + 1 < NCH) issueB(c + 1, (c + 1) & 1);
        const short* Bb = Bs + (c & 1) * 4096;
        const int kc = c & 7;
        bf16x8 af[4], bfr[4];
        #pragma unroll
        for (int mi = 0; mi < 4; ++mi)
            af[mi] = *(const bf16x8*)(As + ((kc * 4 + quad) * 128 + wm * 64 + mi * 16 + l16) * 8);
        #pragma unroll
        for (int ni = 0; ni < 4; ++ni)
            bfr[ni] = *(const bf16x8*)(Bb + (quad * 128 + wn * 64 + ni * 16 + l16) * 8);
        #pragma unroll
        for (int mi = 0; mi < 4; ++mi)
            #pragma unroll
            for (int ni = 0; ni < 4; ++ni)
                acc[mi][ni] = __builtin_amdgcn_mfma_f32_16x16x32_bf16(
                    af[mi], bfr[ni], acc[mi][ni], 0, 0, 0);

        if (kc == 7) {                          // tile complete -> fused epilogue
            const int n0t = (g + NGRP * (c >> 3)) * 128;
            int nIdx[4], nLab[4];
            #pragma unroll
            for (int ni = 0; ni < 4; ++ni) {
                const int n = n0t + wn * 64 + ni * 16 + l16;
                nIdx[ni] = n;
                nLab[ni] = (n < NC) ? clab[n] : -1;
            }
            #pragma unroll
            for (int mi = 0; mi < 4; ++mi) {
                #pragma unroll
                for (int r = 0; r < 4; ++r) {
                    const int m = m0 + wm * 64 + mi * 16 + quad * 4 + r;
                    const int mlab = (m * 5243) >> 19;
                    float s = 0.f, p = 0.f;
                    #pragma unroll
                    for (int ni = 0; ni < 4; ++ni) {
                        const int n = nIdx[ni];
                        if (n < NC && n != m) {
                            const float l = acc[mi][ni][r] * 10.0f;
                            s += __expf(l);
                            if (nLab[ni] == mlab) p += l;
                        }
                    }
                    #pragma unroll
                    for (int o = 1; o < 16; o <<= 1) {
                        s += __shfl_xor(s, o, 64);
                        p += __shfl_xor(p, o, 64);
                    }
                    if (l16 == 0 && m < NA) {
                        atomicAdd(&rowS[m], s);
                        atomicAdd(&rowP[m], p);
                    }
                }
            }
            #pragma unroll
            for (int mi = 0; mi < 4; ++mi)
                #pragma unroll
                for (int ni = 0; ni < 4; ++ni)
                    acc[mi][ni] = f32x4{};
        }
    }

    // ---- fused finalize: last block computes the loss ----
    __syncthreads();
    int* flag = (int*)(lds + 32768);            // Bs area is free now
    if (tid == 0) {
        __threadfence();
        const int o = atomicAdd(ticket, 1);
        flag[0] = (o == NT_M * NGRP - 1) ? 1 : 0;
    }
    __syncthreads();
    if (flag[0]) {
        __threadfence();
        float sum = 0.f;
        for (int n = tid; n < NA; n += 256) {
            const int cls = (n * 5243) >> 19;
            const float cnt = 99.0f + (float)hist[cls];
            const float logS = logf(rowS[n] + 1e-12f);
            sum += (rowP[n] - cnt * logS) / cnt;
        }
        #pragma unroll
        for (int o = 32; o; o >>= 1) sum += __shfl_xor(sum, o, 64);
        float* rs = (float*)lds;
        if (lane == 0) rs[w] = sum;
        __syncthreads();
        if (tid == 0) out[0] = -(10.0f / 7.0f) * ((rs[0] + rs[1] + rs[2] + rs[3]) / 1900.0f);
    }
}

extern "C" void kernel_launch(void* const* d_in, const int* in_sizes, int n_in,
                              void* d_out, int out_size, void* d_ws, size_t ws_size,
                              hipStream_t stream) {
    const float* pixel  = (const float*)d_in[0];   // [8,256,128,128]
    const int*   labels = (const int*)d_in[1];     // [8,128,128]
    const float* mem    = (const float*)d_in[2];   // [20000,256]
    const int*   memlab = (const int*)d_in[3];     // [20000]
    char* ws = (char*)d_ws;
    int*   idx  = (int*)(ws + WS_IDX);
    float* rowS = (float*)(ws + WS_ROWS);
    float* rowP = (float*)(ws + WS_ROWP);
    int*   hist = (int*)(ws + WS_HIST);
    int*   tkt  = (int*)(ws + WS_TKT);
    int*   clab = (int*)(ws + WS_CLAB);
    short* Ct2  = (short*)(ws + WS_CT2);
    float* out  = (float*)d_out;

    prep_kernel<<<dim3(2587), dim3(256), 0, stream>>>(mem, memlab, rowS, rowP, clab, hist, tkt, Ct2);
    sample_kernel<<<dim3(NCLS), dim3(256), 0, stream>>>(labels, idx);
    anchor_kernel<<<dim3(238), dim3(256), 0, stream>>>(pixel, idx, Ct2);
    gemm_kernel<<<dim3(NT_M, NGRP), dim3(256), 0, stream>>>(Ct2, clab, rowS, rowP, hist, tkt, out);
}